// Round 8
// baseline (519.717 us; speedup 1.0000x reference)
//
#include <hip/hip_runtime.h>
#include <hip/hip_bf16.h>
#include <math.h>

#define DIMC 768
#define HEADS 12
#define DHD 64
#define NB 16
#define NP 1024
#define NQKV (3*DIMC)

typedef __attribute__((ext_vector_type(8))) short bf16x8;
typedef __attribute__((ext_vector_type(4))) float f32x4;

__device__ __forceinline__ short f2bf(float f){
  unsigned u = __builtin_bit_cast(unsigned, f);
  u = (u + 0x7fffu + ((u >> 16) & 1u)) >> 16;
  return (short)u;
}
__device__ __forceinline__ float bf2f(short s){
  return __builtin_bit_cast(float, ((unsigned)(unsigned short)s) << 16);
}
__device__ __forceinline__ bf16x8 cvt8(float4 a, float4 b){
  bf16x8 v;
  v[0]=f2bf(a.x); v[1]=f2bf(a.y); v[2]=f2bf(a.z); v[3]=f2bf(a.w);
  v[4]=f2bf(b.x); v[5]=f2bf(b.y); v[6]=f2bf(b.z); v[7]=f2bf(b.w);
  return v;
}
__device__ __forceinline__ void glds16(const void* gsrc, void* ldst){
  __builtin_amdgcn_global_load_lds(
      (const __attribute__((address_space(1))) unsigned int*)gsrc,
      (__attribute__((address_space(3))) unsigned int*)ldst, 16, 0, 0);
}
// physical block -> logical work id, contiguous chunk per XCD (requires nwg%8==0)
__device__ __forceinline__ int xcd_swz(int p, int nwg){
  return (p & 7) * (nwg >> 3) + (p >> 3);
}

// fp32 -> bf16 bulk convert, 8 elems/thread
__global__ __launch_bounds__(256) void cvt_bf16(const float* __restrict__ in, short* __restrict__ out, int n8)
{
  int i = blockIdx.x*256 + threadIdx.x;
  if (i < n8) {
    float4 f0 = ((const float4*)in)[i*2];
    float4 f1 = ((const float4*)in)[i*2+1];
    ((bf16x8*)out)[i] = cvt8(f0, f1);
  }
}

// C[M,N] = A[M,K] @ B[N,K]^T + bias. A,B bf16 via global_load_lds.
// QSCALE=1: scale columns n<768 by 0.125*log2e (folds attn scale+exp2 into Q).
template<int OUTBF16, int QSCALE>
__global__ __launch_bounds__(256) void gemm_bt(
    const short* __restrict__ A, const short* __restrict__ B,
    const float* __restrict__ bias, void* __restrict__ Cp,
    int N, int K, int NX)
{
  __shared__ __align__(16) short As[128*32];
  __shared__ __align__(16) short Bs[128*32];
  const int l = xcd_swz(blockIdx.x, gridDim.x);
  const int bn = (l % NX) * 128, bm = (l / NX) * 128;
  const int t = threadIdx.x;
  const int lane = t & 63, w = t >> 6;
  const int wr = w >> 1, wc = w & 1;
  const int lr = lane & 15, lg = lane >> 4;
  const int srow = lane >> 2;
  const int acol = (lane & 3) * 8;

  f32x4 acc[4][4] = {};

  for (int k0 = 0; k0 < K; k0 += 32) {
    glds16(A + (size_t)(bm + w*32 +  0 + srow)*K + k0 + acol, &As[(w*32 +  0)*32]);
    glds16(A + (size_t)(bm + w*32 + 16 + srow)*K + k0 + acol, &As[(w*32 + 16)*32]);
    glds16(B + (size_t)(bn + w*32 +  0 + srow)*K + k0 + acol, &Bs[(w*32 +  0)*32]);
    glds16(B + (size_t)(bn + w*32 + 16 + srow)*K + k0 + acol, &Bs[(w*32 + 16)*32]);
    __syncthreads();
    bf16x8 a[4], b[4];
    #pragma unroll
    for (int i=0;i<4;i++) a[i] = *(const bf16x8*)&As[(wr*64 + i*16 + lr)*32 + lg*8];
    #pragma unroll
    for (int i=0;i<4;i++) b[i] = *(const bf16x8*)&Bs[(wc*64 + i*16 + lr)*32 + lg*8];
    #pragma unroll
    for (int mf=0;mf<4;mf++)
      #pragma unroll
      for (int nf=0;nf<4;nf++)
        acc[mf][nf] = __builtin_amdgcn_mfma_f32_16x16x32_bf16(a[mf], b[nf], acc[mf][nf], 0,0,0);
    __syncthreads();
  }
  #pragma unroll
  for (int nf=0;nf<4;nf++){
    const int n = bn + wc*64 + nf*16 + lr;
    const float bb = bias[n];
    const float sc = (QSCALE && n < DIMC) ? 0.18033688011112042f : 1.0f;
    #pragma unroll
    for (int mf=0;mf<4;mf++)
      #pragma unroll
      for (int i=0;i<4;i++){
        const int m = bm + wr*64 + mf*16 + lg*4 + i;
        const float v = (acc[mf][nf][i] + bb) * sc;
        if (OUTBF16) ((short*)Cp)[(size_t)m*N + n] = f2bf(v);
        else         ((float*)Cp)[(size_t)m*N + n] = v;
      }
  }
}

// transpose V slice of qkv -> vT[bh][64][1024], rows pre-scaled by 1/colsum
__global__ __launch_bounds__(256) void vtrans(const short* __restrict__ qkv,
                                              const float* __restrict__ invs,
                                              short* __restrict__ vT)
{
  __shared__ __align__(16) short Ts[64][72];
  __shared__ float invl[64];
  const int pt = blockIdx.x, h = blockIdx.y, b = blockIdx.z;
  const int t = threadIdx.x;
  const size_t bh = (size_t)(b*HEADS + h);
  if (t < 64) invl[t] = invs[bh*NP + pt*64 + t];
  {
    const int r = t >> 2, q = t & 3;
    const short* src = qkv + (size_t)(b*NP + pt*64 + r)*NQKV + 2*DIMC + h*DHD + q*16;
    *(bf16x8*)&Ts[r][q*16]   = *(const bf16x8*)src;
    *(bf16x8*)&Ts[r][q*16+8] = *(const bf16x8*)(src+8);
  }
  __syncthreads();
  {
    const int d = t >> 2, q = t & 3;
    __align__(16) short tmp[16];
    #pragma unroll
    for (int j=0;j<16;j++) tmp[j] = f2bf(bf2f(Ts[q*16 + j][d]) * invl[q*16 + j]);
    short* dst = vT + (bh*DHD + d)*NP + pt*64 + q*16;
    *(bf16x8*)dst     = *(bf16x8*)&tmp[0];
    *(bf16x8*)(dst+8) = *(bf16x8*)&tmp[8];
  }
}

// per-column (key) sum of exp2(Q'K^T); K panel in registers, no LDS staging.
__global__ __launch_bounds__(256) void col_stats(const short* __restrict__ qkv, float* __restrict__ invs)
{
  __shared__ float red[4][128];
  const int l = xcd_swz(blockIdx.x, gridDim.x);
  const int kc = l & 7, h = (l >> 3) % HEADS, b = l / (8*HEADS);
  const int t = threadIdx.x;
  const int lane = t & 63, w = t >> 6;
  const int lr = lane & 15, lg = lane >> 4;
  const size_t rowbase = (size_t)(b*NP)*NQKV + h*DHD;
  // preload K panel fragments: k rows kc*128 + kf*16 + lr, d cols hh*32 + lg*8
  bf16x8 kb[8][2];
  #pragma unroll
  for (int kf=0; kf<8; kf++)
    #pragma unroll
    for (int hh=0; hh<2; hh++)
      kb[kf][hh] = *(const bf16x8*)(qkv + rowbase + (size_t)(kc*128 + kf*16 + lr)*NQKV + DIMC + hh*32 + lg*8);
  float rsum[8] = {};
  // wave w handles q sub-blocks sb = w*16 .. w*16+15 (16 q-rows each)
  for (int jj=0; jj<16; jj++){
    const int sb = w*16 + jj;
    const short* qrow = qkv + rowbase + (size_t)(sb*16 + lr)*NQKV + lg*8;
    bf16x8 qa0 = *(const bf16x8*)qrow;
    bf16x8 qa1 = *(const bf16x8*)(qrow + 32);
    #pragma unroll
    for (int kf=0; kf<8; kf++){
      f32x4 acc = {};
      acc = __builtin_amdgcn_mfma_f32_16x16x32_bf16(qa0, kb[kf][0], acc, 0,0,0);
      acc = __builtin_amdgcn_mfma_f32_16x16x32_bf16(qa1, kb[kf][1], acc, 0,0,0);
      #pragma unroll
      for (int i=0;i<4;i++) rsum[kf] += exp2f(acc[i]);
    }
  }
  #pragma unroll
  for (int kf=0;kf<8;kf++){
    float v = rsum[kf];
    v += __shfl_xor(v, 16);
    v += __shfl_xor(v, 32);
    if (lane < 16) red[w][kf*16 + lr] = v;
  }
  __syncthreads();
  if (t < 128) {
    float s = red[0][t] + red[1][t] + red[2][t] + red[3][t];
    invs[(size_t)(b*HEADS + h)*NP + kc*128 + t] = 1.0f / s;
  }
}

// E = exp2(Q'K^T) via swapped mfma(K,Q); MSA = E @ (V*inv).
// No K/V/Q LDS staging (L2-resident); barrier-free; P via b64 LDS round-trip.
__global__ __launch_bounds__(256) void attn_pv(const short* __restrict__ qkv, const short* __restrict__ vT,
                                               short* __restrict__ msa)
{
  __shared__ __align__(16) short Ps[4][16][72];
  const int l = xcd_swz(blockIdx.x, gridDim.x);
  const int qt2 = l & 7, h = (l >> 3) % HEADS, b = l / (8*HEADS);
  const int t = threadIdx.x;
  const int lane = t & 63, w = t >> 6;
  const int lr = lane & 15, lg = lane >> 4;
  const size_t qkvbase = (size_t)(b*NP)*NQKV + h*DHD;
  const size_t bh = (size_t)(b*HEADS + h);
  // Q fragments (B-operand role): q row = qt2*128 + w*32 + g*16 + lr, d col = hh*32 + lg*8
  bf16x8 qa[2][2];
  {
    const short* Qbase = qkv + qkvbase + (size_t)(qt2*128 + w*32 + lr)*NQKV + lg*8;
    #pragma unroll
    for (int g=0; g<2; g++)
      #pragma unroll
      for (int hh=0; hh<2; hh++)
        qa[g][hh] = *(const bf16x8*)(Qbase + (size_t)g*16*NQKV + hh*32);
  }
  const short* Kbase = qkv + qkvbase + DIMC + (size_t)lr*NQKV + lg*8;
  const short* Vbase = vT + (bh*DHD + lr)*NP + lg*8;
  f32x4 o[2][4] = {};
  for (int kt=0; kt<16; kt++){
    bf16x8 kb[4][2], vb[4][2];
    #pragma unroll
    for (int kf=0; kf<4; kf++)
      #pragma unroll
      for (int hh=0; hh<2; hh++)
        kb[kf][hh] = *(const bf16x8*)(Kbase + (size_t)(kt*64 + kf*16)*NQKV + hh*32);
    #pragma unroll
    for (int df=0; df<4; df++)
      #pragma unroll
      for (int kk=0; kk<2; kk++)
        vb[df][kk] = *(const bf16x8*)(Vbase + (size_t)df*16*NP + kt*64 + kk*32);
    #pragma unroll
    for (int g=0; g<2; g++){
      #pragma unroll
      for (int kf=0; kf<4; kf++){
        f32x4 s = {};
        s = __builtin_amdgcn_mfma_f32_16x16x32_bf16(kb[kf][0], qa[g][0], s, 0,0,0);
        s = __builtin_amdgcn_mfma_f32_16x16x32_bf16(kb[kf][1], qa[g][1], s, 0,0,0);
        // lane holds P[q=lr][k = kt*64 + kf*16 + lg*4 + i]
        float e0 = exp2f(s[0]), e1 = exp2f(s[1]), e2 = exp2f(s[2]), e3 = exp2f(s[3]);
        unsigned u0, u1;
        asm("v_cvt_pk_bf16_f32 %0, %1, %2" : "=v"(u0) : "v"(e0), "v"(e1));
        asm("v_cvt_pk_bf16_f32 %0, %1, %2" : "=v"(u1) : "v"(e2), "v"(e3));
        uint2 uu; uu.x = u0; uu.y = u1;
        *(uint2*)&Ps[w][lr][kf*16 + lg*4] = uu;
      }
      // A-frag of P: row q=lr, cols kk*32 + lg*8 (wave-private, in-order LDS)
      bf16x8 pa0 = *(const bf16x8*)&Ps[w][lr][lg*8];
      bf16x8 pa1 = *(const bf16x8*)&Ps[w][lr][32 + lg*8];
      #pragma unroll
      for (int df=0; df<4; df++){
        o[g][df] = __builtin_amdgcn_mfma_f32_16x16x32_bf16(pa0, vb[df][0], o[g][df], 0,0,0);
        o[g][df] = __builtin_amdgcn_mfma_f32_16x16x32_bf16(pa1, vb[df][1], o[g][df], 0,0,0);
      }
    }
  }
  #pragma unroll
  for (int g=0; g<2; g++)
    #pragma unroll
    for (int df=0; df<4; df++){
      const int d = h*DHD + df*16 + lr;
      #pragma unroll
      for (int i=0;i<4;i++){
        const int p = qt2*128 + w*32 + g*16 + lg*4 + i;
        msa[((size_t)(b*NP) + p)*DIMC + d] = f2bf(o[g][df][i]);
      }
    }
}

extern "C" void kernel_launch(void* const* d_in, const int* in_sizes, int n_in,
                              void* d_out, int out_size, void* d_ws, size_t ws_size,
                              hipStream_t stream)
{
  const float* x    = (const float*)d_in[0];
  const float* Wqkv = (const float*)d_in[1];
  const float* bqkv = (const float*)d_in[2];
  const float* Wo   = (const float*)d_in[3];
  const float* bo   = (const float*)d_in[4];
  char* ws = (char*)d_ws;
  short* qkv   = (short*)ws;                     // 75,497,472  bf16 [16384][2304]
  short* vT    = (short*)(ws + 75497472);        // 25,165,824  bf16 [192][64][1024]
  short* Wqkvb = vT;                             // alias: dead before vtrans writes
  short* msa   = (short*)(ws + 100663296);       // 25,165,824  bf16 [16384][768]
  short* xb    = msa;                            // alias: dead before attn_pv writes
  float* invs  = (float*)(ws + 125829120);       //    786,432  f32  [192][1024]
  short* Wob   = qkv;                            // alias: qkv dead after attn_pv

  cvt_bf16<<<6144, 256, 0, stream>>>(x, xb, (16384*768)/8);
  cvt_bf16<<<864, 256, 0, stream>>>(Wqkv, Wqkvb, (2304*768)/8);
  gemm_bt<1,1><<<2304, 256, 0, stream>>>(xb, Wqkvb, bqkv, qkv, NQKV, DIMC, 18);
  col_stats<<<1536, 256, 0, stream>>>(qkv, invs);
  vtrans<<<dim3(16, HEADS, NB), 256, 0, stream>>>(qkv, invs, vT);
  attn_pv<<<1536, 256, 0, stream>>>(qkv, vT, msa);
  cvt_bf16<<<288, 256, 0, stream>>>(Wo, Wob, (768*768)/8);
  gemm_bt<0,0><<<768, 256, 0, stream>>>(msa, Wob, bo, d_out, DIMC, DIMC, 6);
}

// Round 9
// 393.886 us; speedup vs baseline: 1.3195x; 1.3195x over previous
//
#include <hip/hip_runtime.h>
#include <hip/hip_bf16.h>
#include <math.h>

#define DIMC 768
#define HEADS 12
#define DHD 64
#define NB 16
#define NP 1024
#define NQKV (3*DIMC)

typedef __attribute__((ext_vector_type(8))) short bf16x8;
typedef __attribute__((ext_vector_type(4))) float f32x4;

__device__ __forceinline__ short f2bf(float f){
  unsigned u = __builtin_bit_cast(unsigned, f);
  u = (u + 0x7fffu + ((u >> 16) & 1u)) >> 16;
  return (short)u;
}
__device__ __forceinline__ float bf2f(short s){
  return __builtin_bit_cast(float, ((unsigned)(unsigned short)s) << 16);
}
__device__ __forceinline__ bf16x8 cvt8(float4 a, float4 b){
  bf16x8 v;
  v[0]=f2bf(a.x); v[1]=f2bf(a.y); v[2]=f2bf(a.z); v[3]=f2bf(a.w);
  v[4]=f2bf(b.x); v[5]=f2bf(b.y); v[6]=f2bf(b.z); v[7]=f2bf(b.w);
  return v;
}
__device__ __forceinline__ void glds16(const void* gsrc, void* ldst){
  __builtin_amdgcn_global_load_lds(
      (const __attribute__((address_space(1))) unsigned int*)gsrc,
      (__attribute__((address_space(3))) unsigned int*)ldst, 16, 0, 0);
}
// physical block -> logical work id, contiguous chunk per XCD (requires nwg%8==0)
__device__ __forceinline__ int xcd_swz(int p, int nwg){
  return (p & 7) * (nwg >> 3) + (p >> 3);
}

// fp32 -> bf16 bulk convert, 8 elems/thread
__global__ __launch_bounds__(256) void cvt_bf16(const float* __restrict__ in, short* __restrict__ out, int n8)
{
  int i = blockIdx.x*256 + threadIdx.x;
  if (i < n8) {
    float4 f0 = ((const float4*)in)[i*2];
    float4 f1 = ((const float4*)in)[i*2+1];
    ((bf16x8*)out)[i] = cvt8(f0, f1);
  }
}

// C[M,N] = A[M,K] @ B[N,K]^T + bias. A,B bf16 via global_load_lds.
// QSCALE=1: scale columns n<768 by 0.125*log2e (folds attn scale+exp2 into Q).
template<int OUTBF16, int QSCALE>
__global__ __launch_bounds__(256) void gemm_bt(
    const short* __restrict__ A, const short* __restrict__ B,
    const float* __restrict__ bias, void* __restrict__ Cp,
    int N, int K, int NX)
{
  __shared__ __align__(16) short As[128*32];
  __shared__ __align__(16) short Bs[128*32];
  const int l = xcd_swz(blockIdx.x, gridDim.x);
  const int bn = (l % NX) * 128, bm = (l / NX) * 128;
  const int t = threadIdx.x;
  const int lane = t & 63, w = t >> 6;
  const int wr = w >> 1, wc = w & 1;
  const int lr = lane & 15, lg = lane >> 4;
  const int srow = lane >> 2;
  const int acol = (lane & 3) * 8;

  f32x4 acc[4][4] = {};

  for (int k0 = 0; k0 < K; k0 += 32) {
    glds16(A + (size_t)(bm + w*32 +  0 + srow)*K + k0 + acol, &As[(w*32 +  0)*32]);
    glds16(A + (size_t)(bm + w*32 + 16 + srow)*K + k0 + acol, &As[(w*32 + 16)*32]);
    glds16(B + (size_t)(bn + w*32 +  0 + srow)*K + k0 + acol, &Bs[(w*32 +  0)*32]);
    glds16(B + (size_t)(bn + w*32 + 16 + srow)*K + k0 + acol, &Bs[(w*32 + 16)*32]);
    __syncthreads();
    bf16x8 a[4], b[4];
    #pragma unroll
    for (int i=0;i<4;i++) a[i] = *(const bf16x8*)&As[(wr*64 + i*16 + lr)*32 + lg*8];
    #pragma unroll
    for (int i=0;i<4;i++) b[i] = *(const bf16x8*)&Bs[(wc*64 + i*16 + lr)*32 + lg*8];
    #pragma unroll
    for (int mf=0;mf<4;mf++)
      #pragma unroll
      for (int nf=0;nf<4;nf++)
        acc[mf][nf] = __builtin_amdgcn_mfma_f32_16x16x32_bf16(a[mf], b[nf], acc[mf][nf], 0,0,0);
    __syncthreads();
  }
  #pragma unroll
  for (int nf=0;nf<4;nf++){
    const int n = bn + wc*64 + nf*16 + lr;
    const float bb = bias[n];
    const float sc = (QSCALE && n < DIMC) ? 0.18033688011112042f : 1.0f;
    #pragma unroll
    for (int mf=0;mf<4;mf++)
      #pragma unroll
      for (int i=0;i<4;i++){
        const int m = bm + wr*64 + mf*16 + lg*4 + i;
        const float v = (acc[mf][nf][i] + bb) * sc;
        if (OUTBF16) ((short*)Cp)[(size_t)m*N + n] = f2bf(v);
        else         ((float*)Cp)[(size_t)m*N + n] = v;
      }
  }
}

// transpose V slice of qkv -> vT[bh][64][1024], rows pre-scaled by 1/colsum
__global__ __launch_bounds__(256) void vtrans(const short* __restrict__ qkv,
                                              const float* __restrict__ invs,
                                              short* __restrict__ vT)
{
  __shared__ __align__(16) short Ts[64][72];
  __shared__ float invl[64];
  const int pt = blockIdx.x, h = blockIdx.y, b = blockIdx.z;
  const int t = threadIdx.x;
  const size_t bh = (size_t)(b*HEADS + h);
  if (t < 64) invl[t] = invs[bh*NP + pt*64 + t];
  {
    const int r = t >> 2, q = t & 3;
    const short* src = qkv + (size_t)(b*NP + pt*64 + r)*NQKV + 2*DIMC + h*DHD + q*16;
    *(bf16x8*)&Ts[r][q*16]   = *(const bf16x8*)src;
    *(bf16x8*)&Ts[r][q*16+8] = *(const bf16x8*)(src+8);
  }
  __syncthreads();
  {
    const int d = t >> 2, q = t & 3;
    __align__(16) short tmp[16];
    #pragma unroll
    for (int j=0;j<16;j++) tmp[j] = f2bf(bf2f(Ts[q*16 + j][d]) * invl[q*16 + j]);
    short* dst = vT + (bh*DHD + d)*NP + pt*64 + q*16;
    *(bf16x8*)dst     = *(bf16x8*)&tmp[0];
    *(bf16x8*)(dst+8) = *(bf16x8*)&tmp[8];
  }
}

// per-column (key) sum of exp2(Q'K^T); LDS-staged (proven R4 version)
__global__ __launch_bounds__(256) void col_stats(const short* __restrict__ qkv, float* __restrict__ invs)
{
  __shared__ __align__(16) short Ks[128][72];
  __shared__ __align__(16) short Qs[64][72];
  __shared__ float red[4][128];
  const int l = xcd_swz(blockIdx.x, gridDim.x);
  const int kc = l & 7, h = (l >> 3) % HEADS, b = l / (8*HEADS);
  const int t = threadIdx.x;
  const int lane = t & 63, w = t >> 6;
  const int lr = lane & 15, lg = lane >> 4, lk = lg*8;
  const size_t rowbase = (size_t)(b*NP)*NQKV + h*DHD;
  {
    const int r = t >> 1, half = t & 1;
    const short* src = qkv + rowbase + (size_t)(kc*128 + r)*NQKV + DIMC + half*32;
    #pragma unroll
    for (int c=0;c<4;c++)
      *(bf16x8*)&Ks[r][half*32 + c*8] = *(const bf16x8*)(src + c*8);
  }
  float rsum[8] = {};
  for (int qt=0; qt<16; qt++){
    __syncthreads();
    {
      const int r = t >> 2, q = t & 3;
      const short* src = qkv + rowbase + (size_t)(qt*64 + r)*NQKV + q*16;
      *(bf16x8*)&Qs[r][q*16]   = *(const bf16x8*)src;
      *(bf16x8*)&Qs[r][q*16+8] = *(const bf16x8*)(src+8);
    }
    __syncthreads();
    bf16x8 qa0 = *(const bf16x8*)&Qs[w*16 + lr][lk];
    bf16x8 qa1 = *(const bf16x8*)&Qs[w*16 + lr][32 + lk];
    #pragma unroll
    for (int kf=0; kf<8; kf++){
      f32x4 acc = {};
      bf16x8 kb0 = *(const bf16x8*)&Ks[kf*16 + lr][lk];
      bf16x8 kb1 = *(const bf16x8*)&Ks[kf*16 + lr][32 + lk];
      acc = __builtin_amdgcn_mfma_f32_16x16x32_bf16(qa0, kb0, acc, 0,0,0);
      acc = __builtin_amdgcn_mfma_f32_16x16x32_bf16(qa1, kb1, acc, 0,0,0);
      #pragma unroll
      for (int i=0;i<4;i++) rsum[kf] += exp2f(acc[i]);
    }
  }
  #pragma unroll
  for (int kf=0;kf<8;kf++){
    float v = rsum[kf];
    v += __shfl_xor(v, 16);
    v += __shfl_xor(v, 32);
    if (lane < 16) red[w][kf*16 + lr] = v;
  }
  __syncthreads();
  if (t < 128) {
    float s = red[0][t] + red[1][t] + red[2][t] + red[3][t];
    invs[(size_t)(b*HEADS + h)*NP + kc*128 + t] = 1.0f / s;
  }
}

// E = exp2(Q'K^T) via swapped mfma(K,Q); MSA = E @ (V*inv).
// K/V staged per-tile via global_load_lds into linear [64][64] with XOR swizzle
// (swizzle applied to global SOURCE col + LDS READ col; glds dest stays linear).
__global__ __launch_bounds__(256) void attn_pv(const short* __restrict__ qkv, const short* __restrict__ vT,
                                               short* __restrict__ msa)
{
  __shared__ __align__(16) short Ks[64*64];
  __shared__ __align__(16) short Vs[64*64];
  __shared__ __align__(16) short Ps[4][16][72];
  const int l = xcd_swz(blockIdx.x, gridDim.x);
  const int qt2 = l & 7, h = (l >> 3) % HEADS, b = l / (8*HEADS);
  const int t = threadIdx.x;
  const int lane = t & 63, w = t >> 6;
  const int lr = lane & 15, lg = lane >> 4;
  const size_t qkvbase = (size_t)(b*NP)*NQKV + h*DHD;
  const size_t bh = (size_t)(b*HEADS + h);
  // Q fragments (B-operand): q row = qt2*128 + w*32 + g*16 + lr, d = hh*32 + lg*8
  bf16x8 qa[2][2];
  {
    const short* Qbase = qkv + qkvbase + (size_t)(qt2*128 + w*32 + lr)*NQKV + lg*8;
    #pragma unroll
    for (int g=0; g<2; g++)
      #pragma unroll
      for (int hh=0; hh<2; hh++)
        qa[g][hh] = *(const bf16x8*)(Qbase + (size_t)g*16*NQKV + hh*32);
  }
  // staging geometry: per issue, 64 lanes fill 8 rows x 128B; lane l -> row +(l>>3), col shorts (l&7)*8
  const int srw = lane >> 3;                  // 0..7 row within 8-row chunk
  const int scol = 8 * ((lane & 7) ^ srw);    // pre-swizzled source col (shorts)
  const int sx = (lr & 7) << 3;               // read-side XOR (shorts)
  const short* Kg = qkv + qkvbase + DIMC;
  const short* Vg = vT + bh*DHD*NP;
  f32x4 o[2][4] = {};
  for (int kt=0; kt<16; kt++){
    #pragma unroll
    for (int j=0; j<2; j++){
      const int r0 = w*16 + j*8;
      glds16(Kg + (size_t)(kt*64 + r0 + srw)*NQKV + scol, &Ks[r0*64]);
      glds16(Vg + (size_t)(r0 + srw)*NP + kt*64 + scol,   &Vs[r0*64]);
    }
    __syncthreads();   // drains vmcnt (glds) before any wave reads the tiles
    bf16x8 kb[4][2], vb[4][2];
    #pragma unroll
    for (int kf=0; kf<4; kf++)
      #pragma unroll
      for (int hh=0; hh<2; hh++)
        kb[kf][hh] = *(const bf16x8*)&Ks[(kf*16 + lr)*64 + ((hh*32 + lg*8) ^ sx)];
    #pragma unroll
    for (int df=0; df<4; df++)
      #pragma unroll
      for (int kk=0; kk<2; kk++)
        vb[df][kk] = *(const bf16x8*)&Vs[(df*16 + lr)*64 + ((kk*32 + lg*8) ^ sx)];
    #pragma unroll
    for (int g=0; g<2; g++){
      #pragma unroll
      for (int kf=0; kf<4; kf++){
        f32x4 s = {};
        s = __builtin_amdgcn_mfma_f32_16x16x32_bf16(kb[kf][0], qa[g][0], s, 0,0,0);
        s = __builtin_amdgcn_mfma_f32_16x16x32_bf16(kb[kf][1], qa[g][1], s, 0,0,0);
        // lane holds P[q=lr][k = kt*64 + kf*16 + lg*4 + i]
        float e0 = exp2f(s[0]), e1 = exp2f(s[1]), e2 = exp2f(s[2]), e3 = exp2f(s[3]);
        unsigned u0, u1;
        asm("v_cvt_pk_bf16_f32 %0, %1, %2" : "=v"(u0) : "v"(e0), "v"(e1));
        asm("v_cvt_pk_bf16_f32 %0, %1, %2" : "=v"(u1) : "v"(e2), "v"(e3));
        uint2 uu; uu.x = u0; uu.y = u1;
        *(uint2*)&Ps[w][lr][kf*16 + lg*4] = uu;
      }
      // A-frag of P: row q=lr, cols lg*8 (wave-private, in-order LDS)
      bf16x8 pa0 = *(const bf16x8*)&Ps[w][lr][lg*8];
      bf16x8 pa1 = *(const bf16x8*)&Ps[w][lr][32 + lg*8];
      #pragma unroll
      for (int df=0; df<4; df++){
        o[g][df] = __builtin_amdgcn_mfma_f32_16x16x32_bf16(pa0, vb[df][0], o[g][df], 0,0,0);
        o[g][df] = __builtin_amdgcn_mfma_f32_16x16x32_bf16(pa1, vb[df][1], o[g][df], 0,0,0);
      }
    }
    __syncthreads();   // protect tiles before next kt overwrites
  }
  #pragma unroll
  for (int g=0; g<2; g++)
    #pragma unroll
    for (int df=0; df<4; df++){
      const int d = h*DHD + df*16 + lr;
      #pragma unroll
      for (int i=0;i<4;i++){
        const int p = qt2*128 + w*32 + g*16 + lg*4 + i;
        msa[((size_t)(b*NP) + p)*DIMC + d] = f2bf(o[g][df][i]);
      }
    }
}

extern "C" void kernel_launch(void* const* d_in, const int* in_sizes, int n_in,
                              void* d_out, int out_size, void* d_ws, size_t ws_size,
                              hipStream_t stream)
{
  const float* x    = (const float*)d_in[0];
  const float* Wqkv = (const float*)d_in[1];
  const float* bqkv = (const float*)d_in[2];
  const float* Wo   = (const float*)d_in[3];
  const float* bo   = (const float*)d_in[4];
  char* ws = (char*)d_ws;
  short* qkv   = (short*)ws;                     // 75,497,472  bf16 [16384][2304]
  short* vT    = (short*)(ws + 75497472);        // 25,165,824  bf16 [192][64][1024]
  short* Wqkvb = vT;                             // alias: dead before vtrans writes
  short* msa   = (short*)(ws + 100663296);       // 25,165,824  bf16 [16384][768]
  short* xb    = msa;                            // alias: dead before attn_pv writes
  float* invs  = (float*)(ws + 125829120);       //    786,432  f32  [192][1024]
  short* Wob   = qkv;                            // alias: qkv dead after attn_pv

  cvt_bf16<<<6144, 256, 0, stream>>>(x, xb, (16384*768)/8);
  cvt_bf16<<<864, 256, 0, stream>>>(Wqkv, Wqkvb, (2304*768)/8);
  gemm_bt<1,1><<<2304, 256, 0, stream>>>(xb, Wqkvb, bqkv, qkv, NQKV, DIMC, 18);
  col_stats<<<1536, 256, 0, stream>>>(qkv, invs);
  vtrans<<<dim3(16, HEADS, NB), 256, 0, stream>>>(qkv, invs, vT);
  attn_pv<<<1536, 256, 0, stream>>>(qkv, vT, msa);
  cvt_bf16<<<288, 256, 0, stream>>>(Wo, Wob, (768*768)/8);
  gemm_bt<0,0><<<768, 256, 0, stream>>>(msa, Wob, bo, d_out, DIMC, DIMC, 6);
}

// Round 10
// 347.479 us; speedup vs baseline: 1.4957x; 1.1336x over previous
//
#include <hip/hip_runtime.h>
#include <hip/hip_bf16.h>
#include <math.h>

#define DIMC 768
#define HEADS 12
#define DHD 64
#define NB 16
#define NP 1024
#define NQKV (3*DIMC)

typedef __attribute__((ext_vector_type(8))) short bf16x8;
typedef __attribute__((ext_vector_type(4))) float f32x4;

__device__ __forceinline__ short f2bf(float f){
  unsigned u = __builtin_bit_cast(unsigned, f);
  u = (u + 0x7fffu + ((u >> 16) & 1u)) >> 16;
  return (short)u;
}
__device__ __forceinline__ float bf2f(short s){
  return __builtin_bit_cast(float, ((unsigned)(unsigned short)s) << 16);
}
__device__ __forceinline__ bf16x8 cvt8(float4 a, float4 b){
  bf16x8 v;
  v[0]=f2bf(a.x); v[1]=f2bf(a.y); v[2]=f2bf(a.z); v[3]=f2bf(a.w);
  v[4]=f2bf(b.x); v[5]=f2bf(b.y); v[6]=f2bf(b.z); v[7]=f2bf(b.w);
  return v;
}
__device__ __forceinline__ void glds16(const void* gsrc, void* ldst){
  __builtin_amdgcn_global_load_lds(
      (const __attribute__((address_space(1))) unsigned int*)gsrc,
      (__attribute__((address_space(3))) unsigned int*)ldst, 16, 0, 0);
}
// physical block -> logical work id, contiguous chunk per XCD (requires nwg%8==0)
__device__ __forceinline__ int xcd_swz(int p, int nwg){
  return (p & 7) * (nwg >> 3) + (p >> 3);
}

// fp32 -> bf16 bulk convert, 8 elems/thread
__global__ __launch_bounds__(256) void cvt_bf16(const float* __restrict__ in, short* __restrict__ out, int n8)
{
  int i = blockIdx.x*256 + threadIdx.x;
  if (i < n8) {
    float4 f0 = ((const float4*)in)[i*2];
    float4 f1 = ((const float4*)in)[i*2+1];
    ((bf16x8*)out)[i] = cvt8(f0, f1);
  }
}

// C[M,N] = A[M,K] @ B[N,K]^T + bias. A,B bf16 via global_load_lds.
// QSCALE=1: scale columns n<768 by 0.125*log2e (folds attn scale+exp2 into Q).
template<int OUTBF16, int QSCALE>
__global__ __launch_bounds__(256) void gemm_bt(
    const short* __restrict__ A, const short* __restrict__ B,
    const float* __restrict__ bias, void* __restrict__ Cp,
    int N, int K, int NX)
{
  __shared__ __align__(16) short As[128*32];
  __shared__ __align__(16) short Bs[128*32];
  const int l = xcd_swz(blockIdx.x, gridDim.x);
  const int bn = (l % NX) * 128, bm = (l / NX) * 128;
  const int t = threadIdx.x;
  const int lane = t & 63, w = t >> 6;
  const int wr = w >> 1, wc = w & 1;
  const int lr = lane & 15, lg = lane >> 4;
  const int srow = lane >> 2;
  const int acol = (lane & 3) * 8;

  f32x4 acc[4][4] = {};

  for (int k0 = 0; k0 < K; k0 += 32) {
    glds16(A + (size_t)(bm + w*32 +  0 + srow)*K + k0 + acol, &As[(w*32 +  0)*32]);
    glds16(A + (size_t)(bm + w*32 + 16 + srow)*K + k0 + acol, &As[(w*32 + 16)*32]);
    glds16(B + (size_t)(bn + w*32 +  0 + srow)*K + k0 + acol, &Bs[(w*32 +  0)*32]);
    glds16(B + (size_t)(bn + w*32 + 16 + srow)*K + k0 + acol, &Bs[(w*32 + 16)*32]);
    __syncthreads();
    bf16x8 a[4], b[4];
    #pragma unroll
    for (int i=0;i<4;i++) a[i] = *(const bf16x8*)&As[(wr*64 + i*16 + lr)*32 + lg*8];
    #pragma unroll
    for (int i=0;i<4;i++) b[i] = *(const bf16x8*)&Bs[(wc*64 + i*16 + lr)*32 + lg*8];
    #pragma unroll
    for (int mf=0;mf<4;mf++)
      #pragma unroll
      for (int nf=0;nf<4;nf++)
        acc[mf][nf] = __builtin_amdgcn_mfma_f32_16x16x32_bf16(a[mf], b[nf], acc[mf][nf], 0,0,0);
    __syncthreads();
  }
  #pragma unroll
  for (int nf=0;nf<4;nf++){
    const int n = bn + wc*64 + nf*16 + lr;
    const float bb = bias[n];
    const float sc = (QSCALE && n < DIMC) ? 0.18033688011112042f : 1.0f;
    #pragma unroll
    for (int mf=0;mf<4;mf++)
      #pragma unroll
      for (int i=0;i<4;i++){
        const int m = bm + wr*64 + mf*16 + lg*4 + i;
        const float v = (acc[mf][nf][i] + bb) * sc;
        if (OUTBF16) ((short*)Cp)[(size_t)m*N + n] = f2bf(v);
        else         ((float*)Cp)[(size_t)m*N + n] = v;
      }
  }
}

// transpose V slice of qkv -> vT[bh][64][1024], rows pre-scaled by 1/colsum
__global__ __launch_bounds__(256) void vtrans(const short* __restrict__ qkv,
                                              const float* __restrict__ invs,
                                              short* __restrict__ vT)
{
  __shared__ __align__(16) short Ts[64][72];
  __shared__ float invl[64];
  const int pt = blockIdx.x, h = blockIdx.y, b = blockIdx.z;
  const int t = threadIdx.x;
  const size_t bh = (size_t)(b*HEADS + h);
  if (t < 64) invl[t] = invs[bh*NP + pt*64 + t];
  {
    const int r = t >> 2, q = t & 3;
    const short* src = qkv + (size_t)(b*NP + pt*64 + r)*NQKV + 2*DIMC + h*DHD + q*16;
    *(bf16x8*)&Ts[r][q*16]   = *(const bf16x8*)src;
    *(bf16x8*)&Ts[r][q*16+8] = *(const bf16x8*)(src+8);
  }
  __syncthreads();
  {
    const int d = t >> 2, q = t & 3;
    __align__(16) short tmp[16];
    #pragma unroll
    for (int j=0;j<16;j++) tmp[j] = f2bf(bf2f(Ts[q*16 + j][d]) * invl[q*16 + j]);
    short* dst = vT + (bh*DHD + d)*NP + pt*64 + q*16;
    *(bf16x8*)dst     = *(bf16x8*)&tmp[0];
    *(bf16x8*)(dst+8) = *(bf16x8*)&tmp[8];
  }
}

// per-column (key) sum of exp2(Q'K^T); LDS-staged (proven R4 version)
__global__ __launch_bounds__(256) void col_stats(const short* __restrict__ qkv, float* __restrict__ invs)
{
  __shared__ __align__(16) short Ks[128][72];
  __shared__ __align__(16) short Qs[64][72];
  __shared__ float red[4][128];
  const int l = xcd_swz(blockIdx.x, gridDim.x);
  const int kc = l & 7, h = (l >> 3) % HEADS, b = l / (8*HEADS);
  const int t = threadIdx.x;
  const int lane = t & 63, w = t >> 6;
  const int lr = lane & 15, lg = lane >> 4, lk = lg*8;
  const size_t rowbase = (size_t)(b*NP)*NQKV + h*DHD;
  {
    const int r = t >> 1, half = t & 1;
    const short* src = qkv + rowbase + (size_t)(kc*128 + r)*NQKV + DIMC + half*32;
    #pragma unroll
    for (int c=0;c<4;c++)
      *(bf16x8*)&Ks[r][half*32 + c*8] = *(const bf16x8*)(src + c*8);
  }
  float rsum[8] = {};
  for (int qt=0; qt<16; qt++){
    __syncthreads();
    {
      const int r = t >> 2, q = t & 3;
      const short* src = qkv + rowbase + (size_t)(qt*64 + r)*NQKV + q*16;
      *(bf16x8*)&Qs[r][q*16]   = *(const bf16x8*)src;
      *(bf16x8*)&Qs[r][q*16+8] = *(const bf16x8*)(src+8);
    }
    __syncthreads();
    bf16x8 qa0 = *(const bf16x8*)&Qs[w*16 + lr][lk];
    bf16x8 qa1 = *(const bf16x8*)&Qs[w*16 + lr][32 + lk];
    #pragma unroll
    for (int kf=0; kf<8; kf++){
      f32x4 acc = {};
      bf16x8 kb0 = *(const bf16x8*)&Ks[kf*16 + lr][lk];
      bf16x8 kb1 = *(const bf16x8*)&Ks[kf*16 + lr][32 + lk];
      acc = __builtin_amdgcn_mfma_f32_16x16x32_bf16(qa0, kb0, acc, 0,0,0);
      acc = __builtin_amdgcn_mfma_f32_16x16x32_bf16(qa1, kb1, acc, 0,0,0);
      #pragma unroll
      for (int i=0;i<4;i++) rsum[kf] += __builtin_amdgcn_exp2f(acc[i]);
    }
  }
  #pragma unroll
  for (int kf=0;kf<8;kf++){
    float v = rsum[kf];
    v += __shfl_xor(v, 16);
    v += __shfl_xor(v, 32);
    if (lane < 16) red[w][kf*16 + lr] = v;
  }
  __syncthreads();
  if (t < 128) {
    float s = red[0][t] + red[1][t] + red[2][t] + red[3][t];
    invs[(size_t)(b*HEADS + h)*NP + kc*128 + t] = 1.0f / s;
  }
}

// E = exp2(Q'K^T) via swapped mfma(K,Q); MSA = E @ (V*inv).
// 2-phase pipeline: double-buffered K/V glds staging, counted vmcnt (never 0
// in-loop), raw s_barrier (no compiler vmcnt-drain). setprio around MFMA.
__global__ __launch_bounds__(256) void attn_pv(const short* __restrict__ qkv, const short* __restrict__ vT,
                                               short* __restrict__ msa)
{
  __shared__ __align__(16) short Ks[2][64*64];
  __shared__ __align__(16) short Vs[2][64*64];
  __shared__ __align__(16) short Ps[4][16][72];
  const int l = xcd_swz(blockIdx.x, gridDim.x);
  const int qt2 = l & 7, h = (l >> 3) % HEADS, b = l / (8*HEADS);
  const int t = threadIdx.x;
  const int lane = t & 63, w = t >> 6;
  const int lr = lane & 15, lg = lane >> 4;
  const size_t qkvbase = (size_t)(b*NP)*NQKV + h*DHD;
  const size_t bh = (size_t)(b*HEADS + h);
  // Q fragments (B-operand): q row = qt2*128 + w*32 + g*16 + lr, d = hh*32 + lg*8
  bf16x8 qa[2][2];
  {
    const short* Qbase = qkv + qkvbase + (size_t)(qt2*128 + w*32 + lr)*NQKV + lg*8;
    #pragma unroll
    for (int g=0; g<2; g++)
      #pragma unroll
      for (int hh=0; hh<2; hh++)
        qa[g][hh] = *(const bf16x8*)(Qbase + (size_t)g*16*NQKV + hh*32);
  }
  // staging: per glds issue, 64 lanes fill 8 rows x 128B; lane -> row +(l>>3), col (l&7)*8 pre-swizzled
  const int srw = lane >> 3;
  const int scol = 8 * ((lane & 7) ^ srw);    // pre-swizzled source col (shorts)
  const int sx = (lr & 7) << 3;               // read-side XOR (shorts)
  const short* kp = qkv + qkvbase + DIMC + (size_t)(w*16 + srw)*NQKV + scol;
  const short* vp = vT + bh*DHD*NP + (size_t)(w*16 + srw)*NP + scol;

  #define STAGE(buf, kt) do { \
    _Pragma("unroll") \
    for (int j=0; j<2; j++){ \
      glds16(kp + (size_t)((kt)*64 + j*8)*NQKV, &Ks[buf][(w*16 + j*8)*64]); \
      glds16(vp + (size_t)(j*8)*NP + (kt)*64,   &Vs[buf][(w*16 + j*8)*64]); \
    } } while(0)

  f32x4 o[2][4] = {};
  STAGE(0, 0);
  int cur = 0;
  for (int kt=0; kt<16; kt++){
    if (kt < 15) {
      STAGE(cur^1, kt+1);
      asm volatile("s_waitcnt vmcnt(4)" ::: "memory");  // tile kt landed; kt+1 in flight
    } else {
      asm volatile("s_waitcnt vmcnt(0)" ::: "memory");
    }
    __builtin_amdgcn_s_barrier();
    #pragma unroll
    for (int g=0; g<2; g++){
      bf16x8 kb0, kb1;
      f32x4 s[4];
      __builtin_amdgcn_s_setprio(1);
      #pragma unroll
      for (int kf=0; kf<4; kf++){
        kb0 = *(const bf16x8*)&Ks[cur][(kf*16 + lr)*64 + ((     lg*8) ^ sx)];
        kb1 = *(const bf16x8*)&Ks[cur][(kf*16 + lr)*64 + ((32 + lg*8) ^ sx)];
        f32x4 z = {};
        z = __builtin_amdgcn_mfma_f32_16x16x32_bf16(kb0, qa[g][0], z, 0,0,0);
        s[kf] = __builtin_amdgcn_mfma_f32_16x16x32_bf16(kb1, qa[g][1], z, 0,0,0);
      }
      __builtin_amdgcn_s_setprio(0);
      #pragma unroll
      for (int kf=0; kf<4; kf++){
        // lane holds E for q=lr, k = kt*64 + kf*16 + lg*4 + i
        float e0 = __builtin_amdgcn_exp2f(s[kf][0]);
        float e1 = __builtin_amdgcn_exp2f(s[kf][1]);
        float e2 = __builtin_amdgcn_exp2f(s[kf][2]);
        float e3 = __builtin_amdgcn_exp2f(s[kf][3]);
        unsigned u0, u1;
        asm("v_cvt_pk_bf16_f32 %0, %1, %2" : "=v"(u0) : "v"(e0), "v"(e1));
        asm("v_cvt_pk_bf16_f32 %0, %1, %2" : "=v"(u1) : "v"(e2), "v"(e3));
        uint2 uu; uu.x = u0; uu.y = u1;
        *(uint2*)&Ps[w][lr][kf*16 + lg*4] = uu;
      }
      // A-frag of P: row q=lr, cols lg*8 (wave-private; compiler inserts lgkm waits)
      bf16x8 pa0 = *(const bf16x8*)&Ps[w][lr][lg*8];
      bf16x8 pa1 = *(const bf16x8*)&Ps[w][lr][32 + lg*8];
      __builtin_amdgcn_s_setprio(1);
      #pragma unroll
      for (int df=0; df<4; df++){
        bf16x8 vb0 = *(const bf16x8*)&Vs[cur][(df*16 + lr)*64 + ((     lg*8) ^ sx)];
        bf16x8 vb1 = *(const bf16x8*)&Vs[cur][(df*16 + lr)*64 + ((32 + lg*8) ^ sx)];
        o[g][df] = __builtin_amdgcn_mfma_f32_16x16x32_bf16(pa0, vb0, o[g][df], 0,0,0);
        o[g][df] = __builtin_amdgcn_mfma_f32_16x16x32_bf16(pa1, vb1, o[g][df], 0,0,0);
      }
      __builtin_amdgcn_s_setprio(0);
    }
    __builtin_amdgcn_s_barrier();   // all waves done reading cur before restage
    cur ^= 1;
  }
  #undef STAGE
  #pragma unroll
  for (int g=0; g<2; g++)
    #pragma unroll
    for (int df=0; df<4; df++){
      const int d = h*DHD + df*16 + lr;
      #pragma unroll
      for (int i=0;i<4;i++){
        const int p = qt2*128 + w*32 + g*16 + lg*4 + i;
        msa[((size_t)(b*NP) + p)*DIMC + d] = f2bf(o[g][df][i]);
      }
    }
}

extern "C" void kernel_launch(void* const* d_in, const int* in_sizes, int n_in,
                              void* d_out, int out_size, void* d_ws, size_t ws_size,
                              hipStream_t stream)
{
  const float* x    = (const float*)d_in[0];
  const float* Wqkv = (const float*)d_in[1];
  const float* bqkv = (const float*)d_in[2];
  const float* Wo   = (const float*)d_in[3];
  const float* bo   = (const float*)d_in[4];
  char* ws = (char*)d_ws;
  short* qkv   = (short*)ws;                     // 75,497,472  bf16 [16384][2304]
  short* vT    = (short*)(ws + 75497472);        // 25,165,824  bf16 [192][64][1024]
  short* Wqkvb = vT;                             // alias: dead before vtrans writes
  short* msa   = (short*)(ws + 100663296);       // 25,165,824  bf16 [16384][768]
  short* xb    = msa;                            // alias: dead before attn_pv writes
  float* invs  = (float*)(ws + 125829120);       //    786,432  f32  [192][1024]
  short* Wob   = qkv;                            // alias: qkv dead after attn_pv

  cvt_bf16<<<6144, 256, 0, stream>>>(x, xb, (16384*768)/8);
  cvt_bf16<<<864, 256, 0, stream>>>(Wqkv, Wqkvb, (2304*768)/8);
  gemm_bt<1,1><<<2304, 256, 0, stream>>>(xb, Wqkvb, bqkv, qkv, NQKV, DIMC, 18);
  col_stats<<<1536, 256, 0, stream>>>(qkv, invs);
  vtrans<<<dim3(16, HEADS, NB), 256, 0, stream>>>(qkv, invs, vT);
  attn_pv<<<1536, 256, 0, stream>>>(qkv, vT, msa);
  cvt_bf16<<<288, 256, 0, stream>>>(Wo, Wob, (768*768)/8);
  gemm_bt<0,0><<<768, 256, 0, stream>>>(msa, Wob, bo, d_out, DIMC, DIMC, 6);
}

// Round 12
// 345.666 us; speedup vs baseline: 1.5035x; 1.0052x over previous
//
#include <hip/hip_runtime.h>
#include <hip/hip_bf16.h>
#include <math.h>

#define DIMC 768
#define HEADS 12
#define DHD 64
#define NB 16
#define NP 1024
#define NQKV (3*DIMC)

typedef __attribute__((ext_vector_type(8))) short bf16x8;
typedef __attribute__((ext_vector_type(4))) float f32x4;

__device__ __forceinline__ short f2bf(float f){
  unsigned u = __builtin_bit_cast(unsigned, f);
  u = (u + 0x7fffu + ((u >> 16) & 1u)) >> 16;
  return (short)u;
}
__device__ __forceinline__ float bf2f(short s){
  return __builtin_bit_cast(float, ((unsigned)(unsigned short)s) << 16);
}
__device__ __forceinline__ bf16x8 cvt8(float4 a, float4 b){
  bf16x8 v;
  v[0]=f2bf(a.x); v[1]=f2bf(a.y); v[2]=f2bf(a.z); v[3]=f2bf(a.w);
  v[4]=f2bf(b.x); v[5]=f2bf(b.y); v[6]=f2bf(b.z); v[7]=f2bf(b.w);
  return v;
}
__device__ __forceinline__ void glds16(const void* gsrc, void* ldst){
  __builtin_amdgcn_global_load_lds(
      (const __attribute__((address_space(1))) unsigned int*)gsrc,
      (__attribute__((address_space(3))) unsigned int*)ldst, 16, 0, 0);
}
// physical block -> logical work id, contiguous chunk per XCD (requires nwg%8==0)
__device__ __forceinline__ int xcd_swz(int p, int nwg){
  return (p & 7) * (nwg >> 3) + (p >> 3);
}

// fp32 -> bf16 bulk convert, 8 elems/thread
__global__ __launch_bounds__(256) void cvt_bf16(const float* __restrict__ in, short* __restrict__ out, int n8)
{
  int i = blockIdx.x*256 + threadIdx.x;
  if (i < n8) {
    float4 f0 = ((const float4*)in)[i*2];
    float4 f1 = ((const float4*)in)[i*2+1];
    ((bf16x8*)out)[i] = cvt8(f0, f1);
  }
}

// C[M,N] = A[M,K] @ B[N,K]^T + bias. A,B bf16 via global_load_lds.
// 2-phase double-buffered pipeline, counted vmcnt, raw barriers, T2 XOR swizzle.
// Swizzle: LDS(row, slot16B) holds global slot ^ ((row>>1)&3); read slot = lg ^ ((row>>1)&3).
// QSCALE=1: scale columns n<768 by 0.125*log2e (folds attn scale+exp2 into Q).
template<int OUTBF16, int QSCALE>
__global__ __launch_bounds__(256) void gemm_bt(
    const short* __restrict__ A, const short* __restrict__ B,
    const float* __restrict__ bias, void* __restrict__ Cp,
    int N, int K, int NX)
{
  __shared__ __align__(16) short As[2][128*32];
  __shared__ __align__(16) short Bs[2][128*32];
  const int l = xcd_swz(blockIdx.x, gridDim.x);
  const int bn = (l % NX) * 128, bm = (l / NX) * 128;
  const int t = threadIdx.x;
  const int lane = t & 63, w = t >> 6;
  const int wr = w >> 1, wc = w & 1;
  const int lr = lane & 15, lg = lane >> 4;
  const int srw = lane >> 2;                        // 0..15 row within 16-row chunk
  const int acol = 8 * ((lane & 3) ^ ((lane >> 3) & 3));  // pre-swizzled source slot
  const int rsx = (lr >> 1) & 3;                    // read-side XOR term

  const short* ap = A + (size_t)(bm + w*32 + srw)*K + acol;
  const short* bp = B + (size_t)(bn + w*32 + srw)*K + acol;

  #define GSTAGE(buf, k0) do { \
    glds16(ap + (k0),        &As[buf][(w*32 +  0)*32]); \
    glds16(ap + 16*K + (k0), &As[buf][(w*32 + 16)*32]); \
    glds16(bp + (k0),        &Bs[buf][(w*32 +  0)*32]); \
    glds16(bp + 16*K + (k0), &Bs[buf][(w*32 + 16)*32]); \
  } while(0)

  f32x4 acc[4][4] = {};
  const int nk = K >> 5;
  GSTAGE(0, 0);
  int cur = 0;
  for (int kt = 0; kt < nk; ++kt) {
    if (kt + 1 < nk) {
      GSTAGE(cur^1, (kt+1)*32);
      asm volatile("s_waitcnt vmcnt(4)" ::: "memory");  // tile kt landed; kt+1 in flight
    } else {
      asm volatile("s_waitcnt vmcnt(0)" ::: "memory");
    }
    __builtin_amdgcn_s_barrier();
    bf16x8 a[4], b[4];
    #pragma unroll
    for (int i=0;i<4;i++) a[i] = *(const bf16x8*)&As[cur][(wr*64 + i*16 + lr)*32 + (lg ^ rsx)*8];
    #pragma unroll
    for (int i=0;i<4;i++) b[i] = *(const bf16x8*)&Bs[cur][(wc*64 + i*16 + lr)*32 + (lg ^ rsx)*8];
    __builtin_amdgcn_s_setprio(1);
    #pragma unroll
    for (int mf=0;mf<4;mf++)
      #pragma unroll
      for (int nf=0;nf<4;nf++)
        acc[mf][nf] = __builtin_amdgcn_mfma_f32_16x16x32_bf16(a[mf], b[nf], acc[mf][nf], 0,0,0);
    __builtin_amdgcn_s_setprio(0);
    __builtin_amdgcn_s_barrier();   // all waves done reading cur before restage
    cur ^= 1;
  }
  #undef GSTAGE
  #pragma unroll
  for (int nf=0;nf<4;nf++){
    const int n = bn + wc*64 + nf*16 + lr;
    const float bb = bias[n];
    const float sc = (QSCALE && n < DIMC) ? 0.18033688011112042f : 1.0f;
    #pragma unroll
    for (int mf=0;mf<4;mf++)
      #pragma unroll
      for (int i=0;i<4;i++){
        const int m = bm + wr*64 + mf*16 + lg*4 + i;
        const float v = (acc[mf][nf][i] + bb) * sc;
        if (OUTBF16) ((short*)Cp)[(size_t)m*N + n] = f2bf(v);
        else         ((float*)Cp)[(size_t)m*N + n] = v;
      }
  }
}

// transpose V slice of qkv -> vT[bh][64][1024], rows pre-scaled by 1/colsum
__global__ __launch_bounds__(256) void vtrans(const short* __restrict__ qkv,
                                              const float* __restrict__ invs,
                                              short* __restrict__ vT)
{
  __shared__ __align__(16) short Ts[64][72];
  __shared__ float invl[64];
  const int pt = blockIdx.x, h = blockIdx.y, b = blockIdx.z;
  const int t = threadIdx.x;
  const size_t bh = (size_t)(b*HEADS + h);
  if (t < 64) invl[t] = invs[bh*NP + pt*64 + t];
  {
    const int r = t >> 2, q = t & 3;
    const short* src = qkv + (size_t)(b*NP + pt*64 + r)*NQKV + 2*DIMC + h*DHD + q*16;
    *(bf16x8*)&Ts[r][q*16]   = *(const bf16x8*)src;
    *(bf16x8*)&Ts[r][q*16+8] = *(const bf16x8*)(src+8);
  }
  __syncthreads();
  {
    const int d = t >> 2, q = t & 3;
    __align__(16) short tmp[16];
    #pragma unroll
    for (int j=0;j<16;j++) tmp[j] = f2bf(bf2f(Ts[q*16 + j][d]) * invl[q*16 + j]);
    short* dst = vT + (bh*DHD + d)*NP + pt*64 + q*16;
    *(bf16x8*)dst     = *(bf16x8*)&tmp[0];
    *(bf16x8*)(dst+8) = *(bf16x8*)&tmp[8];
  }
}

// per-column (key) sum of exp2(Q'K^T); LDS-staged (proven R4 version)
__global__ __launch_bounds__(256) void col_stats(const short* __restrict__ qkv, float* __restrict__ invs)
{
  __shared__ __align__(16) short Ks[128][72];
  __shared__ __align__(16) short Qs[64][72];
  __shared__ float red[4][128];
  const int l = xcd_swz(blockIdx.x, gridDim.x);
  const int kc = l & 7, h = (l >> 3) % HEADS, b = l / (8*HEADS);
  const int t = threadIdx.x;
  const int lane = t & 63, w = t >> 6;
  const int lr = lane & 15, lg = lane >> 4, lk = lg*8;
  const size_t rowbase = (size_t)(b*NP)*NQKV + h*DHD;
  {
    const int r = t >> 1, half = t & 1;
    const short* src = qkv + rowbase + (size_t)(kc*128 + r)*NQKV + DIMC + half*32;
    #pragma unroll
    for (int c=0;c<4;c++)
      *(bf16x8*)&Ks[r][half*32 + c*8] = *(const bf16x8*)(src + c*8);
  }
  float rsum[8] = {};
  for (int qt=0; qt<16; qt++){
    __syncthreads();
    {
      const int r = t >> 2, q = t & 3;
      const short* src = qkv + rowbase + (size_t)(qt*64 + r)*NQKV + q*16;
      *(bf16x8*)&Qs[r][q*16]   = *(const bf16x8*)src;
      *(bf16x8*)&Qs[r][q*16+8] = *(const bf16x8*)(src+8);
    }
    __syncthreads();
    bf16x8 qa0 = *(const bf16x8*)&Qs[w*16 + lr][lk];
    bf16x8 qa1 = *(const bf16x8*)&Qs[w*16 + lr][32 + lk];
    #pragma unroll
    for (int kf=0; kf<8; kf++){
      f32x4 acc = {};
      bf16x8 kb0 = *(const bf16x8*)&Ks[kf*16 + lr][lk];
      bf16x8 kb1 = *(const bf16x8*)&Ks[kf*16 + lr][32 + lk];
      acc = __builtin_amdgcn_mfma_f32_16x16x32_bf16(qa0, kb0, acc, 0,0,0);
      acc = __builtin_amdgcn_mfma_f32_16x16x32_bf16(qa1, kb1, acc, 0,0,0);
      #pragma unroll
      for (int i=0;i<4;i++) rsum[kf] += __builtin_amdgcn_exp2f(acc[i]);
    }
  }
  #pragma unroll
  for (int kf=0;kf<8;kf++){
    float v = rsum[kf];
    v += __shfl_xor(v, 16);
    v += __shfl_xor(v, 32);
    if (lane < 16) red[w][kf*16 + lr] = v;
  }
  __syncthreads();
  if (t < 128) {
    float s = red[0][t] + red[1][t] + red[2][t] + red[3][t];
    invs[(size_t)(b*HEADS + h)*NP + kc*128 + t] = 1.0f / s;
  }
}

// E = exp2(Q'K^T) via swapped mfma(K,Q); MSA = E @ (V*inv).
// 2-phase pipeline: double-buffered K/V glds staging, counted vmcnt, raw barriers.
__global__ __launch_bounds__(256) void attn_pv(const short* __restrict__ qkv, const short* __restrict__ vT,
                                               short* __restrict__ msa)
{
  __shared__ __align__(16) short Ks[2][64*64];
  __shared__ __align__(16) short Vs[2][64*64];
  __shared__ __align__(16) short Ps[4][16][72];
  const int l = xcd_swz(blockIdx.x, gridDim.x);
  const int qt2 = l & 7, h = (l >> 3) % HEADS, b = l / (8*HEADS);
  const int t = threadIdx.x;
  const int lane = t & 63, w = t >> 6;
  const int lr = lane & 15, lg = lane >> 4;
  const size_t qkvbase = (size_t)(b*NP)*NQKV + h*DHD;
  const size_t bh = (size_t)(b*HEADS + h);
  bf16x8 qa[2][2];
  {
    const short* Qbase = qkv + qkvbase + (size_t)(qt2*128 + w*32 + lr)*NQKV + lg*8;
    #pragma unroll
    for (int g=0; g<2; g++)
      #pragma unroll
      for (int hh=0; hh<2; hh++)
        qa[g][hh] = *(const bf16x8*)(Qbase + (size_t)g*16*NQKV + hh*32);
  }
  const int srw = lane >> 3;
  const int scol = 8 * ((lane & 7) ^ srw);    // pre-swizzled source col (shorts)
  const int sx = (lr & 7) << 3;               // read-side XOR (shorts)
  const short* kp = qkv + qkvbase + DIMC + (size_t)(w*16 + srw)*NQKV + scol;
  const short* vp = vT + bh*DHD*NP + (size_t)(w*16 + srw)*NP + scol;

  #define STAGE(buf, kt) do { \
    _Pragma("unroll") \
    for (int j=0; j<2; j++){ \
      glds16(kp + (size_t)((kt)*64 + j*8)*NQKV, &Ks[buf][(w*16 + j*8)*64]); \
      glds16(vp + (size_t)(j*8)*NP + (kt)*64,   &Vs[buf][(w*16 + j*8)*64]); \
    } } while(0)

  f32x4 o[2][4] = {};
  STAGE(0, 0);
  int cur = 0;
  for (int kt=0; kt<16; kt++){
    if (kt < 15) {
      STAGE(cur^1, kt+1);
      asm volatile("s_waitcnt vmcnt(4)" ::: "memory");
    } else {
      asm volatile("s_waitcnt vmcnt(0)" ::: "memory");
    }
    __builtin_amdgcn_s_barrier();
    #pragma unroll
    for (int g=0; g<2; g++){
      bf16x8 kb0, kb1;
      f32x4 s[4];
      __builtin_amdgcn_s_setprio(1);
      #pragma unroll
      for (int kf=0; kf<4; kf++){
        kb0 = *(const bf16x8*)&Ks[cur][(kf*16 + lr)*64 + ((     lg*8) ^ sx)];
        kb1 = *(const bf16x8*)&Ks[cur][(kf*16 + lr)*64 + ((32 + lg*8) ^ sx)];
        f32x4 z = {};
        z = __builtin_amdgcn_mfma_f32_16x16x32_bf16(kb0, qa[g][0], z, 0,0,0);
        s[kf] = __builtin_amdgcn_mfma_f32_16x16x32_bf16(kb1, qa[g][1], z, 0,0,0);
      }
      __builtin_amdgcn_s_setprio(0);
      #pragma unroll
      for (int kf=0; kf<4; kf++){
        float e0 = __builtin_amdgcn_exp2f(s[kf][0]);
        float e1 = __builtin_amdgcn_exp2f(s[kf][1]);
        float e2 = __builtin_amdgcn_exp2f(s[kf][2]);
        float e3 = __builtin_amdgcn_exp2f(s[kf][3]);
        unsigned u0, u1;
        asm("v_cvt_pk_bf16_f32 %0, %1, %2" : "=v"(u0) : "v"(e0), "v"(e1));
        asm("v_cvt_pk_bf16_f32 %0, %1, %2" : "=v"(u1) : "v"(e2), "v"(e3));
        uint2 uu; uu.x = u0; uu.y = u1;
        *(uint2*)&Ps[w][lr][kf*16 + lg*4] = uu;
      }
      bf16x8 pa0 = *(const bf16x8*)&Ps[w][lr][lg*8];
      bf16x8 pa1 = *(const bf16x8*)&Ps[w][lr][32 + lg*8];
      __builtin_amdgcn_s_setprio(1);
      #pragma unroll
      for (int df=0; df<4; df++){
        bf16x8 vb0 = *(const bf16x8*)&Vs[cur][(df*16 + lr)*64 + ((     lg*8) ^ sx)];
        bf16x8 vb1 = *(const bf16x8*)&Vs[cur][(df*16 + lr)*64 + ((32 + lg*8) ^ sx)];
        o[g][df] = __builtin_amdgcn_mfma_f32_16x16x32_bf16(pa0, vb0, o[g][df], 0,0,0);
        o[g][df] = __builtin_amdgcn_mfma_f32_16x16x32_bf16(pa1, vb1, o[g][df], 0,0,0);
      }
      __builtin_amdgcn_s_setprio(0);
    }
    __builtin_amdgcn_s_barrier();
    cur ^= 1;
  }
  #undef STAGE
  #pragma unroll
  for (int g=0; g<2; g++)
    #pragma unroll
    for (int df=0; df<4; df++){
      const int d = h*DHD + df*16 + lr;
      #pragma unroll
      for (int i=0;i<4;i++){
        const int p = qt2*128 + w*32 + g*16 + lg*4 + i;
        msa[((size_t)(b*NP) + p)*DIMC + d] = f2bf(o[g][df][i]);
      }
    }
}

extern "C" void kernel_launch(void* const* d_in, const int* in_sizes, int n_in,
                              void* d_out, int out_size, void* d_ws, size_t ws_size,
                              hipStream_t stream)
{
  const float* x    = (const float*)d_in[0];
  const float* Wqkv = (const float*)d_in[1];
  const float* bqkv = (const float*)d_in[2];
  const float* Wo   = (const float*)d_in[3];
  const float* bo   = (const float*)d_in[4];
  char* ws = (char*)d_ws;
  short* qkv   = (short*)ws;                     // 75,497,472  bf16 [16384][2304]
  short* vT    = (short*)(ws + 75497472);        // 25,165,824  bf16 [192][64][1024]
  short* Wqkvb = vT;                             // alias: dead before vtrans writes
  short* msa   = (short*)(ws + 100663296);       // 25,165,824  bf16 [16384][768]
  short* xb    = msa;                            // alias: dead before attn_pv writes
  float* invs  = (float*)(ws + 125829120);       //    786,432  f32  [192][1024]
  short* Wob   = qkv;                            // alias: qkv dead after attn_pv

  cvt_bf16<<<6144, 256, 0, stream>>>(x, xb, (16384*768)/8);
  cvt_bf16<<<864, 256, 0, stream>>>(Wqkv, Wqkvb, (2304*768)/8);
  gemm_bt<1,1><<<2304, 256, 0, stream>>>(xb, Wqkvb, bqkv, qkv, NQKV, DIMC, 18);
  col_stats<<<1536, 256, 0, stream>>>(qkv, invs);
  vtrans<<<dim3(16, HEADS, NB), 256, 0, stream>>>(qkv, invs, vT);
  attn_pv<<<1536, 256, 0, stream>>>(qkv, vT, msa);
  cvt_bf16<<<288, 256, 0, stream>>>(Wo, Wob, (768*768)/8);
  gemm_bt<0,0><<<768, 256, 0, stream>>>(msa, Wob, bo, d_out, DIMC, DIMC, 6);
}